// Round 2
// baseline (428.378 us; speedup 1.0000x reference)
//
#include <hip/hip_runtime.h>
#include <hip/hip_fp16.h>
#include <stdint.h>

static constexpr int CI = 16;
static constexpr int CO = 32;
static constexpr int H  = 300000;
static constexpr int K  = 27;
static constexpr float BN_EPS = 1e-5f;

// ---------- f16 helpers ----------
typedef _Float16 h2_t __attribute__((ext_vector_type(2)));

__device__ __forceinline__ unsigned int pack_f16(float lo, float hi) {
    union { h2_t h; unsigned int u; } v;
    v.h[0] = (_Float16)lo;
    v.h[1] = (_Float16)hi;
    return v.u;
}

// acc += a.lo*b.lo + a.hi*b.hi  (v_dot2_f32_f16)
__device__ __forceinline__ float dot2f(unsigned int a, unsigned int b, float c) {
#if __has_builtin(__builtin_amdgcn_fdot2)
    union { unsigned int u; h2_t h; } ua, ub;
    ua.u = a; ub.u = b;
    return __builtin_amdgcn_fdot2(ua.h, ub.h, c, false);
#else
    union { unsigned int u; h2_t h; } ua, ub;
    ua.u = a; ub.u = b;
    float r = fmaf((float)ua.h[0], (float)ub.h[0], c);
    return fmaf((float)ua.h[1], (float)ub.h[1], r);
#endif
}

// ---------- kernel 1: fused prep ----------
__global__ __launch_bounds__(256) void prep(const float* __restrict__ x,
                                            const float* __restrict__ w,
                                            unsigned int* __restrict__ xTp,
                                            unsigned int* __restrict__ wp,
                                            float* __restrict__ stats) {
    int h = blockIdx.x * 256 + threadIdx.x;
    if (h < H) {
        unsigned int r[8];
        #pragma unroll
        for (int j = 0; j < 8; ++j)
            r[j] = pack_f16(x[(size_t)(2 * j) * H + h], x[(size_t)(2 * j + 1) * H + h]);
        uint4* dst = reinterpret_cast<uint4*>(xTp + (size_t)h * 8);
        dst[0] = make_uint4(r[0], r[1], r[2], r[3]);
        dst[1] = make_uint4(r[4], r[5], r[6], r[7]);
    }
    if (blockIdx.x == 0) {
        for (int idx = threadIdx.x; idx < K * CO * 8; idx += 256) {
            int j = idx & 7;
            int o = (idx >> 3) & 31;
            int k = idx >> 8;
            float lo = w[((size_t)o * CI + 2 * j) * K + k];
            float hi = w[((size_t)o * CI + 2 * j + 1) * K + k];
            wp[idx] = pack_f16(lo, hi);
        }
        if (threadIdx.x < 64) stats[threadIdx.x] = 0.f;   // gsum[32] ++ gsq[32]
    }
}

// ---------- kernel 2: gathered conv (f16 dot2) + fused BN stats ----------
// k-split dedup: 256 threads = 128 h. Waves 0-1 (kh=0) process k in [0,14),
// waves 2-3 (kh=1) process k in [14,27) — SAME h set, ALL 32 outputs each.
// Every (h,k) row gather is issued exactly once (vs twice in the split-output
// version), while total wave count stays at 9376 (the latency-hiding level
// that measured 191 us). Weight addresses remain wave-uniform (k is a scalar
// loop var, kh is readfirstlane) -> s_load weights. Partials combine via LDS
// (aliased over the neighbor buffer, stride 36 dwords to spread banks).
__global__ __launch_bounds__(256) void conv(const unsigned int* __restrict__ xTp,
                                            const unsigned int* __restrict__ wp,
                                            const int* __restrict__ neigh,
                                            float* __restrict__ out,
                                            float* __restrict__ stats) {
    __shared__ float comb[128 * 36];                  // 18432 B; first 13824 B alias snb
    int* snb = reinterpret_cast<int*>(comb);

    const int t  = threadIdx.x;
    const int hl = t & 127;
    const int kh = __builtin_amdgcn_readfirstlane(t >> 7);   // wave-uniform 0/1
    const int h  = blockIdx.x * 128 + hl;

    // stage this block's neighbor indices coalesced into LDS (nontemporal stream)
    {
        const int base = blockIdx.x * 128 * K;
        #pragma unroll 1
        for (int s = t; s < 128 * K; s += 256) {
            int g = base + s;
            snb[s] = (g < H * K) ? __builtin_nontemporal_load(&neigh[g]) : -1;
        }
    }
    __syncthreads();

    float acc[32];
    #pragma unroll
    for (int o = 0; o < 32; ++o) acc[o] = 0.f;

    const int k0   = kh * 14;          // kh=0: [0,14)   kh=1: [14,27)
    const int kend = 14 + kh * 13;

    if (h < H) {
        const int* np = &snb[hl * K];

        // prologue: prefetch k = k0
        int idx = np[k0];
        const uint4* p0 = reinterpret_cast<const uint4*>(
            xTp + (size_t)(idx < 0 ? 0 : idx) * 8);
        uint4 a = p0[0];
        uint4 b = p0[1];

        for (int k = k0; k < kend; ++k) {
            const int nidx = (k + 1 < kend) ? np[k + 1] : 0;
            const uint4* p1 = reinterpret_cast<const uint4*>(
                xTp + (size_t)(nidx < 0 ? 0 : nidx) * 8);
            uint4 na = p1[0];
            uint4 nb = p1[1];

            if (idx < 0) {                      // cndmask zero for invalid neighbor
                a.x = a.y = a.z = a.w = 0u;
                b.x = b.y = b.z = b.w = 0u;
            }

            const unsigned int* wk = wp + k * 256;   // wave-uniform -> scalar loads
            #pragma unroll
            for (int o = 0; o < 32; ++o) {
                float s = acc[o];
                s = dot2f(a.x, wk[o * 8 + 0], s);
                s = dot2f(a.y, wk[o * 8 + 1], s);
                s = dot2f(a.z, wk[o * 8 + 2], s);
                s = dot2f(a.w, wk[o * 8 + 3], s);
                s = dot2f(b.x, wk[o * 8 + 4], s);
                s = dot2f(b.y, wk[o * 8 + 5], s);
                s = dot2f(b.z, wk[o * 8 + 6], s);
                s = dot2f(b.w, wk[o * 8 + 7], s);
                acc[o] = s;
            }

            idx = nidx; a = na; b = nb;
        }
    }

    __syncthreads();                                  // all snb reads done
    if (kh == 1) {                                    // upper-k partials -> LDS
        float* c = &comb[hl * 36];                    // 144 B stride, 16B aligned
        #pragma unroll
        for (int o = 0; o < 32; ++o) c[o] = acc[o];
    }
    __syncthreads();

    if (kh == 0) {
        const float* c = &comb[hl * 36];
        #pragma unroll
        for (int o = 0; o < 32; ++o) acc[o] += c[o];  // tail h>=H: 0 + 0

        if (h < H) {
            #pragma unroll
            for (int o = 0; o < 32; ++o)
                out[(size_t)o * H + h] = acc[o];      // coalesced over h
        }

        // fused BN statistics: butterfly per output, one atomic per wave per output
        const unsigned lane = t & 63u;
        float mySum = 0.f, mySq = 0.f;
        #pragma unroll
        for (int o = 0; o < 32; ++o) {
            float v = acc[o];
            float q = v * v;
            #pragma unroll
            for (int d = 32; d > 0; d >>= 1) {
                v += __shfl_xor(v, d, 64);
                q += __shfl_xor(q, d, 64);
            }
            if (lane == (unsigned)o) { mySum = v; mySq = q; }
        }
        if (lane < 32u) {
            atomicAdd(&stats[lane], mySum);           // gsum
            atomicAdd(&stats[32 + lane], mySq);       // gsq
        }
    }
}

// ---------- kernel 3: BN apply ----------
__global__ __launch_bounds__(256) void bn_apply(float* __restrict__ out,
                                                const float* __restrict__ stats,
                                                const float* __restrict__ gamma,
                                                const float* __restrict__ beta) {
    size_t t = (size_t)blockIdx.x * 256 + threadIdx.x;
    size_t base = t * 4;
    if (base >= (size_t)CO * H) return;
    int o = (int)(base / (size_t)H);     // H % 4 == 0 -> float4 never crosses channels
    const float invH = 1.f / (float)H;
    float m   = stats[o] * invH;
    float var = stats[32 + o] * invH - m * m;
    float inv = rsqrtf(var + BN_EPS);
    float sc  = gamma[o] * inv;
    float sh  = beta[o] - m * sc;
    float4* p = reinterpret_cast<float4*>(out + base);
    float4 q = *p;
    q.x = q.x * sc + sh;
    q.y = q.y * sc + sh;
    q.z = q.z * sc + sh;
    q.w = q.w * sc + sh;
    *p = q;
}

// ---------- launch ----------
extern "C" void kernel_launch(void* const* d_in, const int* in_sizes, int n_in,
                              void* d_out, int out_size, void* d_ws, size_t ws_size,
                              hipStream_t stream) {
    const float* x     = (const float*)d_in[0];   // fp32 (1,CI,H,1)
    const float* w     = (const float*)d_in[1];   // fp32 (CO,CI,K)
    const float* gamma = (const float*)d_in[2];   // fp32 (CO)
    const float* beta  = (const float*)d_in[3];   // fp32 (CO)
    const int*   neigh = (const int*)d_in[4];     // int32 (H,K)
    float*       out   = (float*)d_out;           // fp32 (CO,H)

    char* ws = (char*)d_ws;
    const size_t XT_OFF    = 0;                    // H*8*4   = 9,600,000 B
    const size_t WP_OFF    = 9600000;              // 6912*4  = 27,648 B
    const size_t STATS_OFF = 9627648;              // 64 floats
    unsigned int* xTp   = (unsigned int*)(ws + XT_OFF);
    unsigned int* wp    = (unsigned int*)(ws + WP_OFF);
    float*        stats = (float*)(ws + STATS_OFF);

    const int HBP = (H + 255) / 256;               // 1172 (prep)
    prep<<<HBP, 256, 0, stream>>>(x, w, xTp, wp, stats);

    const int HBC = (H + 127) / 128;               // 2344 (conv: 128 h, k-split halves)
    conv<<<HBC, 256, 0, stream>>>(xTp, wp, neigh, out, stats);

    const int NBN = (CO * H / 4 + 255) / 256;      // 9375
    bn_apply<<<NBN, 256, 0, stream>>>(out, stats, gamma, beta);
}

// Round 4
// 336.966 us; speedup vs baseline: 1.2713x; 1.2713x over previous
//
#include <hip/hip_runtime.h>
#include <hip/hip_fp16.h>
#include <stdint.h>

static constexpr int CI = 16;
static constexpr int CO = 32;
static constexpr int H  = 300000;
static constexpr int K  = 27;
static constexpr float BN_EPS = 1e-5f;

// ---------- f16 helpers ----------
typedef _Float16 h2_t __attribute__((ext_vector_type(2)));

__device__ __forceinline__ unsigned int pack_f16(float lo, float hi) {
    union { h2_t h; unsigned int u; } v;
    v.h[0] = (_Float16)lo;
    v.h[1] = (_Float16)hi;
    return v.u;
}

// acc += a.lo*b.lo + a.hi*b.hi  (v_dot2_f32_f16)
__device__ __forceinline__ float dot2f(unsigned int a, unsigned int b, float c) {
#if __has_builtin(__builtin_amdgcn_fdot2)
    union { unsigned int u; h2_t h; } ua, ub;
    ua.u = a; ub.u = b;
    return __builtin_amdgcn_fdot2(ua.h, ub.h, c, false);
#else
    union { unsigned int u; h2_t h; } ua, ub;
    ua.u = a; ub.u = b;
    float r = fmaf((float)ua.h[0], (float)ub.h[0], c);
    return fmaf((float)ua.h[1], (float)ub.h[1], r);
#endif
}

// ---------- kernel 1: fused prep ----------
// x fp32 (CI,H) -> xTp f16-pair rows (H x 8 dwords, 32 B/row);
// w fp32 (o,i,k) -> wp[(k*32+o)*8+j] = (w[o,2j,k], w[o,2j+1,k]) f16 pairs;
// zero stats[64].
__global__ __launch_bounds__(256) void prep(const float* __restrict__ x,
                                            const float* __restrict__ w,
                                            unsigned int* __restrict__ xTp,
                                            unsigned int* __restrict__ wp,
                                            float* __restrict__ stats) {
    int h = blockIdx.x * 256 + threadIdx.x;
    if (h < H) {
        unsigned int r[8];
        #pragma unroll
        for (int j = 0; j < 8; ++j)
            r[j] = pack_f16(x[(size_t)(2 * j) * H + h], x[(size_t)(2 * j + 1) * H + h]);
        uint4* dst = reinterpret_cast<uint4*>(xTp + (size_t)h * 8);
        dst[0] = make_uint4(r[0], r[1], r[2], r[3]);
        dst[1] = make_uint4(r[4], r[5], r[6], r[7]);
    }
    if (blockIdx.x == 0) {
        for (int idx = threadIdx.x; idx < K * CO * 8; idx += 256) {
            int j = idx & 7;
            int o = (idx >> 3) & 31;
            int k = idx >> 8;
            float lo = w[((size_t)o * CI + 2 * j) * K + k];
            float hi = w[((size_t)o * CI + 2 * j + 1) * K + k];
            wp[idx] = pack_f16(lo, hi);
        }
        if (threadIdx.x < 64) stats[threadIdx.x] = 0.f;   // gsum[32] ++ gsq[32]
    }
}

// one pipeline stage: issue gather for row (k_+2) into (anx,bnx,inx),
// then consume row k_ from (acur,bcur,icur). All compile-time-static regs.
__device__ __forceinline__ void conv_stage(int k_, const int* np,
                                           const unsigned int* xTp,
                                           const unsigned int* wh,
                                           float (&acc)[16],
                                           uint4& acur, uint4& bcur, int& icur,
                                           uint4& anx,  uint4& bnx,  int& inx) {
    const int kk = k_ + 2;
    inx = (kk < K) ? np[kk] : 0;
    const uint4* p = reinterpret_cast<const uint4*>(
        xTp + (size_t)(inx < 0 ? 0 : inx) * 8);
    anx = p[0];
    bnx = p[1];

    uint4 a = acur, b = bcur;
    if (icur < 0) {                         // cndmask zero for invalid neighbor
        a.x = a.y = a.z = a.w = 0u;
        b.x = b.y = b.z = b.w = 0u;
    }
    const unsigned int* wk = wh + k_ * 256; // wave-uniform -> scalar loads
    #pragma unroll
    for (int o = 0; o < 16; ++o) {
        float s = acc[o];
        s = dot2f(a.x, wk[o * 8 + 0], s);
        s = dot2f(a.y, wk[o * 8 + 1], s);
        s = dot2f(a.z, wk[o * 8 + 2], s);
        s = dot2f(a.w, wk[o * 8 + 3], s);
        s = dot2f(b.x, wk[o * 8 + 4], s);
        s = dot2f(b.y, wk[o * 8 + 5], s);
        s = dot2f(b.z, wk[o * 8 + 6], s);
        s = dot2f(b.w, wk[o * 8 + 7], s);
        acc[o] = s;
    }
}

// ---------- kernel 2: gathered conv (f16 dot2) + fused BN stats ----------
// R0 structure (2 threads/h split by output halves, acc[16], 9376 waves —
// the known-good occupancy config) + DEPTH-2 gather pipeline: while
// computing row k, rows k+1 AND k+2 are in flight (4 outstanding dwordx4
// loads/thread vs 2). R1/R2 established the kernel is concurrency-starved
// on the random-gather path, not rate-saturated. 3-way rotated register
// sets, no runtime-indexed arrays (K = 27 = 9*3, no tail).
__global__ __launch_bounds__(256) void conv(const unsigned int* __restrict__ xTp,
                                            const unsigned int* __restrict__ wp,
                                            const int* __restrict__ neigh,
                                            float* __restrict__ out,
                                            float* __restrict__ stats) {
    __shared__ int snb[128 * K];
    const int t    = threadIdx.x;
    const int hl   = t & 127;
    const int half = __builtin_amdgcn_readfirstlane(t >> 7);   // wave-uniform 0/1
    const int h    = blockIdx.x * 128 + hl;

    // stage this block's neighbor indices coalesced into LDS (nontemporal stream)
    {
        const int base = blockIdx.x * 128 * K;
        #pragma unroll 1
        for (int s = t; s < 128 * K; s += 256) {
            int g = base + s;
            snb[s] = (g < H * K) ? __builtin_nontemporal_load(&neigh[g]) : -1;
        }
    }
    __syncthreads();

    float acc[16];
    #pragma unroll
    for (int o = 0; o < 16; ++o) acc[o] = 0.f;

    if (h < H) {
        const int* np = &snb[hl * K];
        const unsigned int* wh = wp + half * 128;   // this half's 16 outputs x 8 pairs

        // three rotating row-register sets
        uint4 a0, b0, a1, b1, a2, b2;
        int i0, i1, i2;

        // prologue: rows 0 and 1 in flight
        i0 = np[0];
        {
            const uint4* p = reinterpret_cast<const uint4*>(
                xTp + (size_t)(i0 < 0 ? 0 : i0) * 8);
            a0 = p[0]; b0 = p[1];
        }
        i1 = np[1];
        {
            const uint4* p = reinterpret_cast<const uint4*>(
                xTp + (size_t)(i1 < 0 ? 0 : i1) * 8);
            a1 = p[0]; b1 = p[1];
        }

        #pragma unroll 1
        for (int j = 0; j < K / 3; ++j) {          // 9 iterations, no tail
            const int k = 3 * j;
            conv_stage(k,     np, xTp, wh, acc, a0, b0, i0, a2, b2, i2);
            conv_stage(k + 1, np, xTp, wh, acc, a1, b1, i1, a0, b0, i0);
            conv_stage(k + 2, np, xTp, wh, acc, a2, b2, i2, a1, b1, i1);
        }

        #pragma unroll
        for (int o = 0; o < 16; ++o)
            out[(size_t)(half * 16 + o) * H + h] = acc[o];   // coalesced over h
    }

    // fused BN statistics: butterfly per output, one atomic per wave per output
    const unsigned lane = t & 63u;
    float mySum = 0.f, mySq = 0.f;
    #pragma unroll
    for (int o = 0; o < 16; ++o) {
        float v = acc[o];
        float q = v * v;
        #pragma unroll
        for (int d = 32; d > 0; d >>= 1) {
            v += __shfl_xor(v, d, 64);
            q += __shfl_xor(q, d, 64);
        }
        if (lane == (unsigned)o) { mySum = v; mySq = q; }
    }
    if (lane < 16u) {
        atomicAdd(&stats[half * 16 + lane], mySum);        // gsum
        atomicAdd(&stats[32 + half * 16 + lane], mySq);    // gsq
    }
}

// ---------- kernel 3: BN apply (scale/shift recomputed per thread from stats) ----------
__global__ __launch_bounds__(256) void bn_apply(float* __restrict__ out,
                                                const float* __restrict__ stats,
                                                const float* __restrict__ gamma,
                                                const float* __restrict__ beta) {
    size_t t = (size_t)blockIdx.x * 256 + threadIdx.x;
    size_t base = t * 4;
    if (base >= (size_t)CO * H) return;
    int o = (int)(base / (size_t)H);     // H % 4 == 0 -> float4 never crosses channels
    const float invH = 1.f / (float)H;
    float m   = stats[o] * invH;
    float var = stats[32 + o] * invH - m * m;
    float inv = rsqrtf(var + BN_EPS);
    float sc  = gamma[o] * inv;
    float sh  = beta[o] - m * sc;
    float4* p = reinterpret_cast<float4*>(out + base);
    float4 q = *p;
    q.x = q.x * sc + sh;
    q.y = q.y * sc + sh;
    q.z = q.z * sc + sh;
    q.w = q.w * sc + sh;
    *p = q;
}

// ---------- launch ----------
extern "C" void kernel_launch(void* const* d_in, const int* in_sizes, int n_in,
                              void* d_out, int out_size, void* d_ws, size_t ws_size,
                              hipStream_t stream) {
    const float* x     = (const float*)d_in[0];   // fp32 (1,CI,H,1)
    const float* w     = (const float*)d_in[1];   // fp32 (CO,CI,K)
    const float* gamma = (const float*)d_in[2];   // fp32 (CO)
    const float* beta  = (const float*)d_in[3];   // fp32 (CO)
    const int*   neigh = (const int*)d_in[4];     // int32 (H,K)
    float*       out   = (float*)d_out;           // fp32 (CO,H)

    char* ws = (char*)d_ws;
    const size_t XT_OFF    = 0;                    // H*8*4   = 9,600,000 B
    const size_t WP_OFF    = 9600000;              // 6912*4  = 27,648 B
    const size_t STATS_OFF = 9627648;              // 64 floats
    unsigned int* xTp   = (unsigned int*)(ws + XT_OFF);
    unsigned int* wp    = (unsigned int*)(ws + WP_OFF);
    float*        stats = (float*)(ws + STATS_OFF);

    const int HBP = (H + 255) / 256;               // 1172 (prep)
    prep<<<HBP, 256, 0, stream>>>(x, w, xTp, wp, stats);

    const int HBC = (H + 127) / 128;               // 2344 (conv: 128 h/block, depth-2 pipe)
    conv<<<HBC, 256, 0, stream>>>(xTp, wp, neigh, out, stats);

    const int NBN = (CO * H / 4 + 255) / 256;      // 9375
    bn_apply<<<NBN, 256, 0, stream>>>(out, stats, gamma, beta);
}